// Round 1
// baseline (110.303 us; speedup 1.0000x reference)
//
#include <hip/hip_runtime.h>

// KGNN head: out[b,g,d] = sum_n ( dot(drug[b,g,:], rel[b,g,n,:]) * ent[b,g,n,d] )
// B=2048, n_shape=64, D=64, N_NEIGHBOR=8  -> 131072 independent groups.
// One 64-lane wave per group; float4 loads (16B/lane); shuffle reductions, no LDS.

constexpr int BATCH   = 2048;
constexpr int NSHAPE  = 64;
constexpr int DIM     = 64;
constexpr int NGROUPS = BATCH * NSHAPE;          // 131072
constexpr int WAVES_PER_BLOCK = 4;               // 256 threads

__global__ __launch_bounds__(256) void kgnn_head_kernel(
    const float* __restrict__ drug,   // [B, 64, 64]
    const float* __restrict__ rel,    // [B, 512, 64]
    const float* __restrict__ ent,    // [B, 512, 64]
    float*       __restrict__ out)    // [B, 64, 64]
{
    const int gid  = (int)((blockIdx.x * blockDim.x + threadIdx.x) >> 6); // group id
    const int lane = threadIdx.x & 63;

    // Per-group flat bases (element counts fit easily in 32-bit; use size_t for bytes)
    const float4* drug4 = reinterpret_cast<const float4*>(drug + (size_t)gid * DIM);
    const float4* rel4  = reinterpret_cast<const float4*>(rel  + (size_t)gid * (8 * DIM));
    const float4* ent4  = reinterpret_cast<const float4*>(ent  + (size_t)gid * (8 * DIM));

    const int seg = lane >> 4;   // which neighbor within the pass (0..3)
    const int pos = lane & 15;   // float4 position within the 64-float row
    (void)seg;

    // drug fragment for this lane's 4 dims (d = pos*4 .. pos*4+3).
    // 4 lanes share each address -> broadcast, served by cache.
    const float4 dg = drug4[pos];

    float4 acc = make_float4(0.f, 0.f, 0.f, 0.f);

    #pragma unroll
    for (int pass = 0; pass < 2; ++pass) {
        // float4 index within the group's 128-float4 chunk:
        //   idx = pass*64 + lane = (pass*4 + seg)*16 + pos  -> neighbor n = pass*4+seg
        const float4 r = rel4[pass * 64 + lane];
        const float4 e = ent4[pass * 64 + lane];

        // partial dot over this lane's 4 dims
        float p = dg.x * r.x + dg.y * r.y + dg.z * r.z + dg.w * r.w;

        // reduce within the 16-lane segment -> score for neighbor n (replicated)
        p += __shfl_xor(p, 1);
        p += __shfl_xor(p, 2);
        p += __shfl_xor(p, 4);
        p += __shfl_xor(p, 8);

        // weighted accumulate of this neighbor's entity fragment
        acc.x = fmaf(p, e.x, acc.x);
        acc.y = fmaf(p, e.y, acc.y);
        acc.z = fmaf(p, e.z, acc.z);
        acc.w = fmaf(p, e.w, acc.w);
    }

    // sum the 4 neighbor-segments (same pos, different seg): lanes l, l^16, l^32, l^48
    acc.x += __shfl_xor(acc.x, 16);
    acc.y += __shfl_xor(acc.y, 16);
    acc.z += __shfl_xor(acc.z, 16);
    acc.w += __shfl_xor(acc.w, 16);
    acc.x += __shfl_xor(acc.x, 32);
    acc.y += __shfl_xor(acc.y, 32);
    acc.z += __shfl_xor(acc.z, 32);
    acc.w += __shfl_xor(acc.w, 32);

    if (lane < 16) {
        float4* o4 = reinterpret_cast<float4*>(out + (size_t)gid * DIM);
        o4[pos] = acc;
    }
}

extern "C" void kernel_launch(void* const* d_in, const int* in_sizes, int n_in,
                              void* d_out, int out_size, void* d_ws, size_t ws_size,
                              hipStream_t stream) {
    const float* drug = (const float*)d_in[0];
    const float* rel  = (const float*)d_in[1];
    const float* ent  = (const float*)d_in[2];
    float* out = (float*)d_out;

    const int blocks = NGROUPS / WAVES_PER_BLOCK;  // 32768
    kgnn_head_kernel<<<blocks, WAVES_PER_BLOCK * 64, 0, stream>>>(drug, rel, ent, out);
}